// Round 8
// baseline (420.937 us; speedup 1.0000x reference)
//
#include <hip/hip_runtime.h>
#include <math.h>

#define TT 256
#define HH 128

__device__ __forceinline__ void enc6(float t, float e[6]) {
  float x = 6.2831853071795864769f * t;
  float a0 = x / 86400.0f, a1 = x / 604800.0f, a2 = x / 2592000.0f;
  e[0] = sinf(a0); e[1] = sinf(a1); e[2] = sinf(a2);
  e[3] = cosf(a0); e[4] = cosf(a1); e[5] = cosf(a2);
}

__device__ __forceinline__ float wave_sum(float s) {
  #pragma unroll
  for (int o = 32; o > 0; o >>= 1) s += __shfl_xor(s, o);
  return s;
}

// blocks 0..2047: embed row; blocks 2048..2055: hper for batch b
__global__ __launch_bounds__(128) void embed_hper_kernel(
    const int* __restrict__ log_seqs, const float* __restrict__ time_seq,
    const float* __restrict__ item_emb, const float* __restrict__ time_proj,
    const float* __restrict__ target_t, const float* __restrict__ pred_W,
    const float* __restrict__ fus_W1, const float* __restrict__ fus_b1,
    float* __restrict__ seqs, float* __restrict__ sc6, float* __restrict__ hp1) {
  int blk = blockIdx.x;
  int tid = threadIdx.x;
  if (blk < 2048) {
    float t = time_seq[blk];
    float e[6]; enc6(t, e);
    int idx = log_seqs[blk];
    const float* tp = time_proj + tid * 6;
    float val = item_emb[(size_t)idx * HH + tid] * 11.313708498984761f; // sqrt(128)
    val += e[0]*tp[0] + e[1]*tp[1] + e[2]*tp[2] + e[3]*tp[3] + e[4]*tp[4] + e[5]*tp[5];
    seqs[(size_t)blk * HH + tid] = (idx != 0) ? val : 0.0f;
    if (tid < 6) sc6[blk * 6 + tid] = e[tid];
  } else {
    int b = blk - 2048;
    __shared__ float te[HH], hp[HH];
    float e[6]; enc6(target_t[b], e);
    const float* tp = time_proj + tid * 6;
    te[tid] = e[0]*tp[0]+e[1]*tp[1]+e[2]*tp[2]+e[3]*tp[3]+e[4]*tp[4]+e[5]*tp[5];
    __syncthreads();
    float u = 0.f;
    const float* pw = pred_W + (size_t)tid * HH;
    for (int d = 0; d < HH; ++d) u += te[d] * pw[d];
    hp[tid] = u;
    __syncthreads();
    float w = fus_b1[tid];
    const float* f1 = fus_W1 + (size_t)tid * 256 + 128;
    for (int d = 0; d < HH; ++d) w += hp[d] * f1[d];
    hp1[b * HH + tid] = w;
  }
}

// 3072 blocks x 256 thr; which = blk>>10 (0=Q+LN, 1=K+absK transposed, 2=V+absV).
// 2 rows/block, 1 output/thread.
__global__ __launch_bounds__(256) void qkv_gemm(
    const float* __restrict__ S,
    const float* __restrict__ Wq, const float* __restrict__ bq,
    const float* __restrict__ Wk, const float* __restrict__ bk,
    const float* __restrict__ Wv, const float* __restrict__ bv,
    const float* __restrict__ lng, const float* __restrict__ lnb,
    const float* __restrict__ absK, const float* __restrict__ absV,
    float* __restrict__ QN, float* __restrict__ QB,
    float* __restrict__ KT, float* __restrict__ VB) {
  int blk = blockIdx.x;
  int which = blk >> 10;
  int m0 = (blk & 1023) * 2;
  int tid = threadIdx.x;
  int r = tid >> 7, n = tid & 127, w = tid >> 6;
  __shared__ float A2[2][HH];
  __shared__ float red[8];
  int m = m0 + r;
  float x = S[(size_t)m * HH + n];
  if (which == 0) {
    float s = wave_sum(x);
    if ((tid & 63) == 0) red[w] = s;
    __syncthreads();
    float mu = (red[r * 2] + red[r * 2 + 1]) * (1.0f / HH);
    float dv = x - mu;
    float v2 = wave_sum(dv * dv);
    if ((tid & 63) == 0) red[4 + w] = v2;
    __syncthreads();
    float var = (red[4 + r * 2] + red[5 + r * 2]) * (1.0f / HH);
    x = dv * rsqrtf(var + 1e-8f) * lng[n] + lnb[n];
    QN[(size_t)m * HH + n] = x;
  }
  A2[r][n] = x;
  __syncthreads();
  const float* W    = which == 0 ? Wq : which == 1 ? Wk : Wv;
  const float* bias = which == 0 ? bq : which == 1 ? bk : bv;
  const float* wr = W + (size_t)n * HH;
  float acc0 = 0.f, acc1 = 0.f;
  #pragma unroll
  for (int d = 0; d < HH; d += 8) {
    float4 w0 = *(const float4*)(wr + d);
    float4 w1 = *(const float4*)(wr + d + 4);
    float4 a0 = *(const float4*)(&A2[r][d]);
    float4 a1 = *(const float4*)(&A2[r][d + 4]);
    acc0 = fmaf(a0.x, w0.x, fmaf(a0.y, w0.y, fmaf(a0.z, w0.z, fmaf(a0.w, w0.w, acc0))));
    acc1 = fmaf(a1.x, w1.x, fmaf(a1.y, w1.y, fmaf(a1.z, w1.z, fmaf(a1.w, w1.w, acc1))));
  }
  float v = acc0 + acc1 + bias[n];
  int t = m & 255;
  if (which == 0) {
    QB[(size_t)m * HH + n] = v;
  } else if (which == 1) {
    v += absK[(size_t)t * HH + n];
    int bb2 = m >> 8, hh2 = n >> 6, dd = n & 63;
    KT[(((size_t)(bb2 * 2 + hh2) * 64) + dd) * 256 + t] = v;
  } else {
    v += absV[(size_t)t * HH + n];
    VB[(size_t)m * HH + n] = v;
  }
}

// SCB[bh,q,k] = mask ? -1e9 : 0.125*(q . tKe[tm[b,q,k]]) + phase_bias(q,k)
// grid: 16 bh x 64 qtiles(4q) = 1024 blocks x 256 thr
__global__ __launch_bounds__(256) void pkscb_kernel(
    const float* __restrict__ QB, const float* __restrict__ tKe,
    const int* __restrict__ tmat, const int* __restrict__ log_seqs,
    const float* __restrict__ sc6, const float* __restrict__ lambdas,
    float* __restrict__ SCB) {
  int blk = blockIdx.x;
  int qt = blk & 63, bh = blk >> 6;
  int h = bh & 1, b = bh >> 1;
  int q0 = qt << 2, hoff = h << 6;
  int tid = threadIdx.x;
  __shared__ float Qs[4][64];
  __shared__ float PKl[4][264];
  __shared__ float sk6T[6][256];
  __shared__ float sq6[4][6];
  __shared__ unsigned char kmask[256];
  { int q = tid >> 6, d = tid & 63;
    Qs[q][d] = QB[((size_t)(b * TT + q0 + q)) * HH + hoff + d]; }
  for (int idx = tid; idx < 1536; idx += 256) {
    int kk = idx / 6, cc = idx - kk * 6;
    sk6T[cc][kk] = sc6[(size_t)b * 1536 + idx];
  }
  if (tid < 24) {
    int q = tid / 6, cc = tid - q * 6;
    sq6[q][cc] = sc6[((size_t)(b * TT + q0 + q)) * 6 + cc];
  }
  kmask[tid] = (log_seqs[b * TT + tid] == 0) ? 1 : 0;
  __syncthreads();
  for (int i = tid; i < 257; i += 256) {
    const float* tp = tKe + (size_t)i * HH + hoff;
    float a0 = 0.f, a1 = 0.f, a2 = 0.f, a3 = 0.f;
    #pragma unroll
    for (int d = 0; d < 64; d += 4) {
      float4 t4 = *(const float4*)(tp + d);
      float4 v0 = *(const float4*)(&Qs[0][d]);
      float4 v1 = *(const float4*)(&Qs[1][d]);
      float4 v2 = *(const float4*)(&Qs[2][d]);
      float4 v3 = *(const float4*)(&Qs[3][d]);
      a0 = fmaf(v0.x,t4.x,fmaf(v0.y,t4.y,fmaf(v0.z,t4.z,fmaf(v0.w,t4.w,a0))));
      a1 = fmaf(v1.x,t4.x,fmaf(v1.y,t4.y,fmaf(v1.z,t4.z,fmaf(v1.w,t4.w,a1))));
      a2 = fmaf(v2.x,t4.x,fmaf(v2.y,t4.y,fmaf(v2.z,t4.z,fmaf(v2.w,t4.w,a2))));
      a3 = fmaf(v3.x,t4.x,fmaf(v3.y,t4.y,fmaf(v3.z,t4.z,fmaf(v3.w,t4.w,a3))));
    }
    PKl[0][i] = a0 * 0.125f; PKl[1][i] = a1 * 0.125f;
    PKl[2][i] = a2 * 0.125f; PKl[3][i] = a3 * 0.125f;
  }
  __syncthreads();
  float l0 = lambdas[0], l1 = lambdas[1], l2 = lambdas[2];
  int k = tid;
  float c0 = sk6T[0][k], c1 = sk6T[1][k], c2 = sk6T[2][k],
        c3 = sk6T[3][k], c4 = sk6T[4][k], c5 = sk6T[5][k];
  int km = kmask[k];
  float* scbq = SCB + ((size_t)(bh * TT + q0)) * TT;
  #pragma unroll
  for (int qq = 0; qq < 4; ++qq) {
    int qg = q0 + qq;
    float pb = l0 * (sq6[qq][0] * c0 + sq6[qq][3] * c3)
             + l1 * (sq6[qq][1] * c1 + sq6[qq][4] * c4)
             + l2 * (sq6[qq][2] * c2 + sq6[qq][5] * c5);
    int tm = tmat[((size_t)(b * TT + qg)) * TT + k];
    float val = (k > qg || km) ? -1e9f : (PKl[qq][tm] + pb);
    scbq[(size_t)qq * TT + k] = val;
  }
}

// grid: 2048 blocks (XCD-swizzled), 256 thr, 2 q-rows per block.
__global__ __launch_bounds__(256) void attn_fused(
    const float* __restrict__ QB, const float* __restrict__ KT,
    const float* __restrict__ VB, const float* __restrict__ QN,
    const float* __restrict__ SCB, const int* __restrict__ tmat,
    const float* __restrict__ tVe, float* __restrict__ out) {
  int blk = blockIdx.x;
  blk = (blk & 7) * 256 + (blk >> 3);   // bijective XCD swizzle (2048 = 8*256)
  int qt = blk & 127;
  int h = (blk >> 7) & 1;
  int b = blk >> 8;
  int q0 = qt << 1;
  int hoff = h << 6;
  int tid = threadIdx.x;
  int w = tid >> 6, lane = tid & 63;

  __shared__ float Qt[2][64];
  __shared__ float Pp[2][256];
  __shared__ unsigned short tmq[2][256];
  __shared__ float part[4][2][64];
  __shared__ float red[16];

  if (tid < 128)
    Qt[tid >> 6][tid & 63] = QB[((size_t)(b * TT + q0 + (tid >> 6))) * HH + hoff + (tid & 63)];
  #pragma unroll
  for (int t = 0; t < 2; ++t) {
    int idx = tid + t * 256;
    int qq = idx >> 8, kk = idx & 255;
    tmq[qq][kk] = (unsigned short)tmat[((size_t)(b * TT + q0 + qq)) * TT + kk];
  }
  __syncthreads();

  int k = (w << 6) | lane;
  const float* scb0 = SCB + ((size_t)((b * 2 + h) * TT + q0)) * TT;
  float s0 = scb0[k];
  float s1 = scb0[TT + k];
  if ((w << 6) <= q0 + 1) {   // wave has at least one causally-valid key
    float a0 = 0.f, a1 = 0.f;
    const float* ktb = KT + ((size_t)((b * 2 + h) * 64)) * 256 + k;
    #pragma unroll
    for (int d4 = 0; d4 < 16; ++d4) {
      float4 qa = *(const float4*)(&Qt[0][d4 << 2]);
      float4 qb = *(const float4*)(&Qt[1][d4 << 2]);
      const float* kp = ktb + (size_t)(d4 << 2) * 256;
      float v0 = kp[0], v1 = kp[256], v2 = kp[512], v3 = kp[768];
      a0 = fmaf(qa.x, v0, fmaf(qa.y, v1, fmaf(qa.z, v2, fmaf(qa.w, v3, a0))));
      a1 = fmaf(qb.x, v0, fmaf(qb.y, v1, fmaf(qb.z, v2, fmaf(qb.w, v3, a1))));
    }
    if (s0 > -5e8f) s0 = fmaf(a0, 0.125f, s0);
    if (s1 > -5e8f) s1 = fmaf(a1, 0.125f, s1);
  }
  float m0 = s0, m1 = s1;
  #pragma unroll
  for (int o = 32; o > 0; o >>= 1) {
    m0 = fmaxf(m0, __shfl_xor(m0, o));
    m1 = fmaxf(m1, __shfl_xor(m1, o));
  }
  if (lane == 0) { red[w] = m0; red[4 + w] = m1; }
  __syncthreads();
  float gm0 = fmaxf(fmaxf(red[0], red[1]), fmaxf(red[2], red[3]));
  float gm1 = fmaxf(fmaxf(red[4], red[5]), fmaxf(red[6], red[7]));
  float p0 = (gm0 < -5e8f) ? 1.0f : __expf(s0 - gm0);  // fully-masked row -> uniform (ref)
  float p1 = (gm1 < -5e8f) ? 1.0f : __expf(s1 - gm1);
  float u0 = p0, u1 = p1;
  #pragma unroll
  for (int o = 32; o > 0; o >>= 1) {
    u0 += __shfl_xor(u0, o);
    u1 += __shfl_xor(u1, o);
  }
  if (lane == 0) { red[8 + w] = u0; red[12 + w] = u1; }
  __syncthreads();
  float inv0 = 1.0f / (red[8] + red[9] + red[10] + red[11]);
  float inv1 = 1.0f / (red[12] + red[13] + red[14] + red[15]);
  Pp[0][k] = p0 * inv0;
  Pp[1][k] = p1 * inv1;
  __syncthreads();

  int kend = (gm0 < -5e8f || gm1 < -5e8f) ? 256 : (q0 + 2);
  float o0 = 0.f, o1 = 0.f;
  const float* vbase = VB + ((size_t)(b * TT)) * HH + hoff + lane;
  const float* tvb   = tVe + hoff + lane;
  for (int kk = w; kk < kend; kk += 4) {
    float pa  = Pp[0][kk];
    float pb2 = Pp[1][kk];
    int ta = tmq[0][kk], tb = tmq[1][kk];
    float v  = vbase[(size_t)kk * HH];
    float t0 = tvb[(size_t)ta * HH];
    float t1 = tvb[(size_t)tb * HH];
    o0 = fmaf(pa,  v + t0, o0);
    o1 = fmaf(pb2, v + t1, o1);
  }
  part[w][0][lane] = o0;
  part[w][1][lane] = o1;
  __syncthreads();
  if (tid < 128) {
    int qq = tid >> 6, d = tid & 63;
    float o = part[0][qq][d] + part[1][qq][d] + part[2][qq][d] + part[3][qq][d];
    size_t ob = ((size_t)(b * TT + q0 + qq)) * HH + hoff + d;
    out[ob] = QN[ob] + o;
  }
}

// 1024 blocks x 256 thr, 2 rows/block: LN + relu(x@W1^T+b1)@W2^T + b2 + x, keep-mask.
__global__ __launch_bounds__(256) void ffn_gemm(
    const float* __restrict__ S, const float* __restrict__ W1, const float* __restrict__ b1,
    const float* __restrict__ W2, const float* __restrict__ b2,
    const float* __restrict__ lng, const float* __restrict__ lnb,
    const int* __restrict__ log_seqs, float* __restrict__ outS) {
  int m0 = blockIdx.x * 2;
  int tid = threadIdx.x;
  int r = tid >> 7, n = tid & 127, w = tid >> 6;
  int m = m0 + r;
  __shared__ float Xt[2][HH];
  __shared__ float Ht[2][HH];
  __shared__ float red[8];
  float x = S[(size_t)m * HH + n];
  float s = wave_sum(x);
  if ((tid & 63) == 0) red[w] = s;
  __syncthreads();
  float mu = (red[r * 2] + red[r * 2 + 1]) * (1.0f / HH);
  float dv = x - mu;
  float v2 = wave_sum(dv * dv);
  if ((tid & 63) == 0) red[4 + w] = v2;
  __syncthreads();
  float var = (red[4 + r * 2] + red[5 + r * 2]) * (1.0f / HH);
  x = dv * rsqrtf(var + 1e-8f) * lng[n] + lnb[n];
  Xt[r][n] = x;
  __syncthreads();
  {
    const float* wr = W1 + (size_t)n * HH;
    float acc0 = 0.f, acc1 = 0.f;
    #pragma unroll
    for (int d = 0; d < HH; d += 8) {
      float4 w0 = *(const float4*)(wr + d);
      float4 w1 = *(const float4*)(wr + d + 4);
      float4 a0 = *(const float4*)(&Xt[r][d]);
      float4 a1 = *(const float4*)(&Xt[r][d + 4]);
      acc0 = fmaf(a0.x, w0.x, fmaf(a0.y, w0.y, fmaf(a0.z, w0.z, fmaf(a0.w, w0.w, acc0))));
      acc1 = fmaf(a1.x, w1.x, fmaf(a1.y, w1.y, fmaf(a1.z, w1.z, fmaf(a1.w, w1.w, acc1))));
    }
    Ht[r][n] = fmaxf(acc0 + acc1 + b1[n], 0.f);
  }
  __syncthreads();
  {
    const float* wr = W2 + (size_t)n * HH;
    float acc0 = 0.f, acc1 = 0.f;
    #pragma unroll
    for (int d = 0; d < HH; d += 8) {
      float4 w0 = *(const float4*)(wr + d);
      float4 w1 = *(const float4*)(wr + d + 4);
      float4 a0 = *(const float4*)(&Ht[r][d]);
      float4 a1 = *(const float4*)(&Ht[r][d + 4]);
      acc0 = fmaf(a0.x, w0.x, fmaf(a0.y, w0.y, fmaf(a0.z, w0.z, fmaf(a0.w, w0.w, acc0))));
      acc1 = fmaf(a1.x, w1.x, fmaf(a1.y, w1.y, fmaf(a1.z, w1.z, fmaf(a1.w, w1.w, acc1))));
    }
    float v = acc0 + acc1 + b2[n] + Xt[r][n];
    if (log_seqs[m] == 0) v = 0.f;
    outS[(size_t)m * HH + n] = v;
  }
}

// 1024 blocks x 256 thr, 2 rows: last LN + gelu(...)@fus_W2^T + logits.
__global__ __launch_bounds__(256) void final_gemm(
    const float* __restrict__ S, const float* __restrict__ lng, const float* __restrict__ lnb,
    const float* __restrict__ fus_W1, const float* __restrict__ HP1,
    const float* __restrict__ fus_W2, const float* __restrict__ fus_b2,
    const float* __restrict__ item_emb, const int* __restrict__ pos,
    const int* __restrict__ neg, float* __restrict__ out) {
  int m0 = blockIdx.x * 2;
  int bidx = m0 >> 8;
  int tid = threadIdx.x;
  int r = tid >> 7, n = tid & 127, w = tid >> 6;
  int lane = tid & 63;
  int m = m0 + r;
  __shared__ float Xt[2][HH];
  __shared__ float Ht[2][HH];
  __shared__ float Ft[2][HH];
  __shared__ float red[8];
  float x = S[(size_t)m * HH + n];
  float s = wave_sum(x);
  if ((tid & 63) == 0) red[w] = s;
  __syncthreads();
  float mu = (red[r * 2] + red[r * 2 + 1]) * (1.0f / HH);
  float dv = x - mu;
  float v2 = wave_sum(dv * dv);
  if ((tid & 63) == 0) red[4 + w] = v2;
  __syncthreads();
  float var = (red[4 + r * 2] + red[5 + r * 2]) * (1.0f / HH);
  Xt[r][n] = dv * rsqrtf(var + 1e-8f) * lng[n] + lnb[n];
  __syncthreads();
  {
    const float* wr = fus_W1 + (size_t)n * 256;
    float acc0 = 0.f, acc1 = 0.f;
    #pragma unroll
    for (int d = 0; d < HH; d += 8) {
      float4 w0 = *(const float4*)(wr + d);
      float4 w1 = *(const float4*)(wr + d + 4);
      float4 a0 = *(const float4*)(&Xt[r][d]);
      float4 a1 = *(const float4*)(&Xt[r][d + 4]);
      acc0 = fmaf(a0.x, w0.x, fmaf(a0.y, w0.y, fmaf(a0.z, w0.z, fmaf(a0.w, w0.w, acc0))));
      acc1 = fmaf(a1.x, w1.x, fmaf(a1.y, w1.y, fmaf(a1.z, w1.z, fmaf(a1.w, w1.w, acc1))));
    }
    float v = acc0 + acc1 + HP1[bidx * HH + n];
    Ht[r][n] = 0.5f * v * (1.0f + erff(v * 0.70710678118654752f));
  }
  __syncthreads();
  {
    const float* wr = fus_W2 + (size_t)n * HH;
    float acc0 = 0.f, acc1 = 0.f;
    #pragma unroll
    for (int d = 0; d < HH; d += 8) {
      float4 w0 = *(const float4*)(wr + d);
      float4 w1 = *(const float4*)(wr + d + 4);
      float4 a0 = *(const float4*)(&Ht[r][d]);
      float4 a1 = *(const float4*)(&Ht[r][d + 4]);
      acc0 = fmaf(a0.x, w0.x, fmaf(a0.y, w0.y, fmaf(a0.z, w0.z, fmaf(a0.w, w0.w, acc0))));
      acc1 = fmaf(a1.x, w1.x, fmaf(a1.y, w1.y, fmaf(a1.z, w1.z, fmaf(a1.w, w1.w, acc1))));
    }
    Ft[r][n] = acc0 + acc1 + fus_b2[n];
  }
  __syncthreads();
  // logits: task w (0..3): row = w&1, pos/neg = w>>1
  {
    int r2 = w & 1;
    int pn = w >> 1;
    int mrow = m0 + r2;
    int idx = pn ? neg[mrow] : pos[mrow];
    const float* ie = item_emb + (size_t)idx * HH;
    float sacc = Ft[r2][lane] * ie[lane] + Ft[r2][lane + 64] * ie[lane + 64];
    sacc = wave_sum(sacc);
    if (lane == 0) out[pn * 2048 + mrow] = sacc;
  }
}

extern "C" void kernel_launch(void* const* d_in, const int* in_sizes, int n_in,
                              void* d_out, int out_size, void* d_ws, size_t ws_size,
                              hipStream_t stream) {
  const int*   log_seqs   = (const int*)d_in[0];
  const int*   tmat       = (const int*)d_in[1];
  const float* time_seq   = (const float*)d_in[2];
  const int*   pos_seqs   = (const int*)d_in[3];
  const int*   neg_seqs   = (const int*)d_in[4];
  const float* target_t   = (const float*)d_in[5];
  const float* item_emb   = (const float*)d_in[6];
  const float* abs_pos_K  = (const float*)d_in[7];
  const float* abs_pos_V  = (const float*)d_in[8];
  const float* time_K_emb = (const float*)d_in[9];
  const float* time_V_emb = (const float*)d_in[10];
  const float* Wq = (const float*)d_in[11];
  const float* bq = (const float*)d_in[12];
  const float* Wk = (const float*)d_in[13];
  const float* bk = (const float*)d_in[14];
  const float* Wv = (const float*)d_in[15];
  const float* bv = (const float*)d_in[16];
  const float* attn_ln_g = (const float*)d_in[17];
  const float* attn_ln_b = (const float*)d_in[18];
  const float* fwd_ln_g = (const float*)d_in[19];
  const float* fwd_ln_b = (const float*)d_in[20];
  const float* w1 = (const float*)d_in[21];
  const float* b1 = (const float*)d_in[22];
  const float* w2 = (const float*)d_in[23];
  const float* b2 = (const float*)d_in[24];
  const float* last_ln_g = (const float*)d_in[25];
  const float* last_ln_b = (const float*)d_in[26];
  const float* time_proj = (const float*)d_in[27];
  const float* lambdas = (const float*)d_in[28];
  const float* pred_W = (const float*)d_in[29];
  const float* fus_W1 = (const float*)d_in[30];
  const float* fus_b1 = (const float*)d_in[31];
  const float* fus_W2 = (const float*)d_in[32];
  const float* fus_b2 = (const float*)d_in[33];
  (void)in_sizes; (void)n_in; (void)out_size; (void)ws_size;

  float* out = (float*)d_out;
  float* ws = (float*)d_ws;
  const int M = 8 * TT;  // 2048
  float* SC6  = ws;                 // M*6
  float* SEQS = SC6 + M * 6;
  float* QN   = SEQS + M * HH;
  float* QB   = QN + M * HH;
  float* KT   = QB + M * HH;        // [b][h][d][t]
  float* VB   = KT + M * HH;
  float* HP1  = VB + M * HH;        // 8*128
  float* SCB  = HP1 + 8 * HH;       // 16*256*256 f32 = 4 MB

  embed_hper_kernel<<<2056, 128, 0, stream>>>(log_seqs, time_seq, item_emb, time_proj,
                                              target_t, pred_W, fus_W1, fus_b1,
                                              SEQS, SC6, HP1);
  for (int l = 0; l < 2; ++l) {
    const size_t wo = (size_t)l * HH * HH;
    const size_t bo = (size_t)l * HH;
    qkv_gemm<<<3072, 256, 0, stream>>>(SEQS, Wq + wo, bq + bo, Wk + wo, bk + bo,
                                       Wv + wo, bv + bo, attn_ln_g + bo, attn_ln_b + bo,
                                       abs_pos_K, abs_pos_V, QN, QB, KT, VB);
    pkscb_kernel<<<1024, 256, 0, stream>>>(QB, time_K_emb, tmat, log_seqs, SC6, lambdas, SCB);
    attn_fused<<<2048, 256, 0, stream>>>(QB, KT, VB, QN, SCB, tmat, time_V_emb, SEQS);
    ffn_gemm<<<1024, 256, 0, stream>>>(SEQS, w1 + wo, b1 + bo, w2 + wo, b2 + bo,
                                       fwd_ln_g + bo, fwd_ln_b + bo, log_seqs, SEQS);
  }
  final_gemm<<<1024, 256, 0, stream>>>(SEQS, last_ln_g, last_ln_b, fus_W1, HP1,
                                       fus_W2, fus_b2, item_emb, pos_seqs, neg_seqs, out);
}

// Round 9
// 320.129 us; speedup vs baseline: 1.3149x; 1.3149x over previous
//
#include <hip/hip_runtime.h>
#include <math.h>

#define TT 256
#define HH 128

__device__ __forceinline__ void enc6(float t, float e[6]) {
  float x = 6.2831853071795864769f * t;
  float a0 = x / 86400.0f, a1 = x / 604800.0f, a2 = x / 2592000.0f;
  e[0] = sinf(a0); e[1] = sinf(a1); e[2] = sinf(a2);
  e[3] = cosf(a0); e[4] = cosf(a1); e[5] = cosf(a2);
}

// blocks 0..2047: embed row; blocks 2048..2055: hper for batch b
__global__ __launch_bounds__(128) void embed_hper_kernel(
    const int* __restrict__ log_seqs, const float* __restrict__ time_seq,
    const float* __restrict__ item_emb, const float* __restrict__ time_proj,
    const float* __restrict__ target_t, const float* __restrict__ pred_W,
    const float* __restrict__ fus_W1, const float* __restrict__ fus_b1,
    float* __restrict__ seqs, float* __restrict__ sc6, float* __restrict__ hp1) {
  int blk = blockIdx.x;
  int tid = threadIdx.x;
  if (blk < 2048) {
    float t = time_seq[blk];
    float e[6]; enc6(t, e);
    int idx = log_seqs[blk];
    const float* tp = time_proj + tid * 6;
    float val = item_emb[(size_t)idx * HH + tid] * 11.313708498984761f; // sqrt(128)
    val += e[0]*tp[0] + e[1]*tp[1] + e[2]*tp[2] + e[3]*tp[3] + e[4]*tp[4] + e[5]*tp[5];
    seqs[(size_t)blk * HH + tid] = (idx != 0) ? val : 0.0f;
    if (tid < 6) sc6[blk * 6 + tid] = e[tid];
  } else {
    int b = blk - 2048;
    __shared__ float te[HH], hp[HH];
    float e[6]; enc6(target_t[b], e);
    const float* tp = time_proj + tid * 6;
    te[tid] = e[0]*tp[0]+e[1]*tp[1]+e[2]*tp[2]+e[3]*tp[3]+e[4]*tp[4]+e[5]*tp[5];
    __syncthreads();
    float u = 0.f;
    const float* pw = pred_W + (size_t)tid * HH;
    for (int d = 0; d < HH; ++d) u += te[d] * pw[d];
    hp[tid] = u;
    __syncthreads();
    float w = fus_b1[tid];
    const float* f1 = fus_W1 + (size_t)tid * 256 + 128;
    for (int d = 0; d < HH; ++d) w += hp[d] * f1[d];
    hp1[b * HH + tid] = w;
  }
}

// LDS-tiled GEMM: 768 blocks x 128 thr; which = blk>>8 (0=Q+LN, 1=K+absK->KT, 2=V+absV).
// 8 rows/block; whole W staged in LDS (pad 129); micro-tile 2 rows x 4 strided cols.
__global__ __launch_bounds__(128) void qkv_tiled(
    const float* __restrict__ S,
    const float* __restrict__ Wq, const float* __restrict__ bq,
    const float* __restrict__ Wk, const float* __restrict__ bk,
    const float* __restrict__ Wv, const float* __restrict__ bv,
    const float* __restrict__ lng, const float* __restrict__ lnb,
    const float* __restrict__ absK, const float* __restrict__ absV,
    float* __restrict__ QN, float* __restrict__ QB,
    float* __restrict__ KT, float* __restrict__ VB) {
  int blk = blockIdx.x;
  int which = blk >> 8;
  int m0 = (blk & 255) * 8;
  int tid = threadIdx.x;
  int c = tid & 31, rg = tid >> 5;
  __shared__ float Ws[128][129];
  __shared__ float At[8][129];
  __shared__ float red[16];
  #pragma unroll
  for (int r = 0; r < 8; ++r) At[r][tid] = S[(size_t)(m0 + r) * HH + tid];
  const float* W = which == 0 ? Wq : which == 1 ? Wk : Wv;
  for (int i = tid; i < 4096; i += 128) {
    int n = i >> 5, d = (i & 31) << 2;
    float4 wv = *(const float4*)(W + (size_t)n * HH + d);
    Ws[n][d] = wv.x; Ws[n][d+1] = wv.y; Ws[n][d+2] = wv.z; Ws[n][d+3] = wv.w;
  }
  __syncthreads();
  if (which == 0) {
    if (tid < 64) {
      int r = tid >> 3, sg = tid & 7;
      float s = 0.f;
      #pragma unroll
      for (int i = 0; i < 16; ++i) s += At[r][sg * 16 + i];
      s += __shfl_xor(s, 1); s += __shfl_xor(s, 2); s += __shfl_xor(s, 4);
      if (sg == 0) red[r] = s * (1.0f / HH);
    }
    __syncthreads();
    if (tid < 64) {
      int r = tid >> 3, sg = tid & 7;
      float mm = red[r], s = 0.f;
      #pragma unroll
      for (int i = 0; i < 16; ++i) { float dd = At[r][sg*16+i] - mm; s += dd * dd; }
      s += __shfl_xor(s, 1); s += __shfl_xor(s, 2); s += __shfl_xor(s, 4);
      if (sg == 0) red[8 + r] = rsqrtf(s * (1.0f / HH) + 1e-8f);
    }
    __syncthreads();
    float gg = lng[tid], bb = lnb[tid];
    #pragma unroll
    for (int r = 0; r < 8; ++r) {
      float v = (At[r][tid] - red[r]) * red[8 + r] * gg + bb;
      At[r][tid] = v;
      QN[(size_t)(m0 + r) * HH + tid] = v;
    }
    __syncthreads();
  }
  float acc[2][4] = {{0.f,0.f,0.f,0.f},{0.f,0.f,0.f,0.f}};
  #pragma unroll 8
  for (int d = 0; d < 128; ++d) {
    float a0 = At[rg * 2 + 0][d];
    float a1 = At[rg * 2 + 1][d];
    float w0 = Ws[c][d], w1 = Ws[c + 32][d], w2 = Ws[c + 64][d], w3 = Ws[c + 96][d];
    acc[0][0] = fmaf(a0, w0, acc[0][0]); acc[0][1] = fmaf(a0, w1, acc[0][1]);
    acc[0][2] = fmaf(a0, w2, acc[0][2]); acc[0][3] = fmaf(a0, w3, acc[0][3]);
    acc[1][0] = fmaf(a1, w0, acc[1][0]); acc[1][1] = fmaf(a1, w1, acc[1][1]);
    acc[1][2] = fmaf(a1, w2, acc[1][2]); acc[1][3] = fmaf(a1, w3, acc[1][3]);
  }
  const float* bias = which == 0 ? bq : which == 1 ? bk : bv;
  #pragma unroll
  for (int ri = 0; ri < 2; ++ri) {
    int m = m0 + rg * 2 + ri;
    int t = m & 255, bb2 = m >> 8;
    #pragma unroll
    for (int j = 0; j < 4; ++j) {
      int n = c + 32 * j;
      float v = acc[ri][j] + bias[n];
      if (which == 0) {
        QB[(size_t)m * HH + n] = v;
      } else if (which == 1) {
        v += absK[(size_t)t * HH + n];
        KT[(((size_t)(bb2 * 2 + (n >> 6)) * 64) + (n & 63)) * 256 + t] = v;
      } else {
        v += absV[(size_t)t * HH + n];
        VB[(size_t)m * HH + n] = v;
      }
    }
  }
}

// SCB[bh,q,k] = mask ? -1e9 : 0.125*(q . tKe[tm[b,q,k]]) + phase_bias(q,k)
__global__ __launch_bounds__(256) void pkscb_kernel(
    const float* __restrict__ QB, const float* __restrict__ tKe,
    const int* __restrict__ tmat, const int* __restrict__ log_seqs,
    const float* __restrict__ sc6, const float* __restrict__ lambdas,
    float* __restrict__ SCB) {
  int blk = blockIdx.x;
  int qt = blk & 63, bh = blk >> 6;
  int h = bh & 1, b = bh >> 1;
  int q0 = qt << 2, hoff = h << 6;
  int tid = threadIdx.x;
  __shared__ float Qs[4][64];
  __shared__ float PKl[4][264];
  __shared__ float sk6T[6][256];
  __shared__ float sq6[4][6];
  __shared__ unsigned char kmask[256];
  { int q = tid >> 6, d = tid & 63;
    Qs[q][d] = QB[((size_t)(b * TT + q0 + q)) * HH + hoff + d]; }
  for (int idx = tid; idx < 1536; idx += 256) {
    int kk = idx / 6, cc = idx - kk * 6;
    sk6T[cc][kk] = sc6[(size_t)b * 1536 + idx];
  }
  if (tid < 24) {
    int q = tid / 6, cc = tid - q * 6;
    sq6[q][cc] = sc6[((size_t)(b * TT + q0 + q)) * 6 + cc];
  }
  kmask[tid] = (log_seqs[b * TT + tid] == 0) ? 1 : 0;
  __syncthreads();
  for (int i = tid; i < 257; i += 256) {
    const float* tp = tKe + (size_t)i * HH + hoff;
    float a0 = 0.f, a1 = 0.f, a2 = 0.f, a3 = 0.f;
    #pragma unroll
    for (int d = 0; d < 64; d += 4) {
      float4 t4 = *(const float4*)(tp + d);
      float4 v0 = *(const float4*)(&Qs[0][d]);
      float4 v1 = *(const float4*)(&Qs[1][d]);
      float4 v2 = *(const float4*)(&Qs[2][d]);
      float4 v3 = *(const float4*)(&Qs[3][d]);
      a0 = fmaf(v0.x,t4.x,fmaf(v0.y,t4.y,fmaf(v0.z,t4.z,fmaf(v0.w,t4.w,a0))));
      a1 = fmaf(v1.x,t4.x,fmaf(v1.y,t4.y,fmaf(v1.z,t4.z,fmaf(v1.w,t4.w,a1))));
      a2 = fmaf(v2.x,t4.x,fmaf(v2.y,t4.y,fmaf(v2.z,t4.z,fmaf(v2.w,t4.w,a2))));
      a3 = fmaf(v3.x,t4.x,fmaf(v3.y,t4.y,fmaf(v3.z,t4.z,fmaf(v3.w,t4.w,a3))));
    }
    PKl[0][i] = a0 * 0.125f; PKl[1][i] = a1 * 0.125f;
    PKl[2][i] = a2 * 0.125f; PKl[3][i] = a3 * 0.125f;
  }
  __syncthreads();
  float l0 = lambdas[0], l1 = lambdas[1], l2 = lambdas[2];
  int k = tid;
  float c0 = sk6T[0][k], c1 = sk6T[1][k], c2 = sk6T[2][k],
        c3 = sk6T[3][k], c4 = sk6T[4][k], c5 = sk6T[5][k];
  int km = kmask[k];
  float* scbq = SCB + ((size_t)(bh * TT + q0)) * TT;
  #pragma unroll
  for (int qq = 0; qq < 4; ++qq) {
    int qg = q0 + qq;
    float pb = l0 * (sq6[qq][0] * c0 + sq6[qq][3] * c3)
             + l1 * (sq6[qq][1] * c1 + sq6[qq][4] * c4)
             + l2 * (sq6[qq][2] * c2 + sq6[qq][5] * c5);
    int tm = tmat[((size_t)(b * TT + qg)) * TT + k];
    float val = (k > qg || km) ? -1e9f : (PKl[qq][tm] + pb);
    scbq[(size_t)qq * TT + k] = val;
  }
}

// grid: 2048 blocks (XCD-swizzled), 256 thr, 2 q-rows per block.
__global__ __launch_bounds__(256) void attn_fused(
    const float* __restrict__ QB, const float* __restrict__ KT,
    const float* __restrict__ VB, const float* __restrict__ QN,
    const float* __restrict__ SCB, const int* __restrict__ tmat,
    const float* __restrict__ tVe, float* __restrict__ out) {
  int blk = blockIdx.x;
  blk = (blk & 7) * 256 + (blk >> 3);   // bijective XCD swizzle (2048 = 8*256)
  int qt = blk & 127;
  int h = (blk >> 7) & 1;
  int b = blk >> 8;
  int q0 = qt << 1;
  int hoff = h << 6;
  int tid = threadIdx.x;
  int w = tid >> 6, lane = tid & 63;

  __shared__ float Qt[2][64];
  __shared__ float Pp[2][256];
  __shared__ unsigned short tmq[2][256];
  __shared__ float part[4][2][64];
  __shared__ float red[16];

  if (tid < 128)
    Qt[tid >> 6][tid & 63] = QB[((size_t)(b * TT + q0 + (tid >> 6))) * HH + hoff + (tid & 63)];
  #pragma unroll
  for (int t = 0; t < 2; ++t) {
    int idx = tid + t * 256;
    int qq = idx >> 8, kk = idx & 255;
    tmq[qq][kk] = (unsigned short)tmat[((size_t)(b * TT + q0 + qq)) * TT + kk];
  }
  __syncthreads();

  int k = (w << 6) | lane;
  const float* scb0 = SCB + ((size_t)((b * 2 + h) * TT + q0)) * TT;
  float s0 = scb0[k];
  float s1 = scb0[TT + k];
  if ((w << 6) <= q0 + 1) {
    float a0 = 0.f, a1 = 0.f;
    const float* ktb = KT + ((size_t)((b * 2 + h) * 64)) * 256 + k;
    #pragma unroll
    for (int d4 = 0; d4 < 16; ++d4) {
      float4 qa = *(const float4*)(&Qt[0][d4 << 2]);
      float4 qb = *(const float4*)(&Qt[1][d4 << 2]);
      const float* kp = ktb + (size_t)(d4 << 2) * 256;
      float v0 = kp[0], v1 = kp[256], v2 = kp[512], v3 = kp[768];
      a0 = fmaf(qa.x, v0, fmaf(qa.y, v1, fmaf(qa.z, v2, fmaf(qa.w, v3, a0))));
      a1 = fmaf(qb.x, v0, fmaf(qb.y, v1, fmaf(qb.z, v2, fmaf(qb.w, v3, a1))));
    }
    if (s0 > -5e8f) s0 = fmaf(a0, 0.125f, s0);
    if (s1 > -5e8f) s1 = fmaf(a1, 0.125f, s1);
  }
  float m0 = s0, m1 = s1;
  #pragma unroll
  for (int o = 32; o > 0; o >>= 1) {
    m0 = fmaxf(m0, __shfl_xor(m0, o));
    m1 = fmaxf(m1, __shfl_xor(m1, o));
  }
  if (lane == 0) { red[w] = m0; red[4 + w] = m1; }
  __syncthreads();
  float gm0 = fmaxf(fmaxf(red[0], red[1]), fmaxf(red[2], red[3]));
  float gm1 = fmaxf(fmaxf(red[4], red[5]), fmaxf(red[6], red[7]));
  float p0 = (gm0 < -5e8f) ? 1.0f : __expf(s0 - gm0);
  float p1 = (gm1 < -5e8f) ? 1.0f : __expf(s1 - gm1);
  float u0 = p0, u1 = p1;
  #pragma unroll
  for (int o = 32; o > 0; o >>= 1) {
    u0 += __shfl_xor(u0, o);
    u1 += __shfl_xor(u1, o);
  }
  if (lane == 0) { red[8 + w] = u0; red[12 + w] = u1; }
  __syncthreads();
  float inv0 = 1.0f / (red[8] + red[9] + red[10] + red[11]);
  float inv1 = 1.0f / (red[12] + red[13] + red[14] + red[15]);
  Pp[0][k] = p0 * inv0;
  Pp[1][k] = p1 * inv1;
  __syncthreads();

  int kend = (gm0 < -5e8f || gm1 < -5e8f) ? 256 : (q0 + 2);
  float o0 = 0.f, o1 = 0.f;
  const float* vbase = VB + ((size_t)(b * TT)) * HH + hoff + lane;
  const float* tvb   = tVe + hoff + lane;
  for (int kk = w; kk < kend; kk += 4) {
    float pa  = Pp[0][kk];
    float pb2 = Pp[1][kk];
    int ta = tmq[0][kk], tb = tmq[1][kk];
    float v  = vbase[(size_t)kk * HH];
    float t0 = tvb[(size_t)ta * HH];
    float t1 = tvb[(size_t)tb * HH];
    o0 = fmaf(pa,  v + t0, o0);
    o1 = fmaf(pb2, v + t1, o1);
  }
  part[w][0][lane] = o0;
  part[w][1][lane] = o1;
  __syncthreads();
  if (tid < 128) {
    int qq = tid >> 6, d = tid & 63;
    float o = part[0][qq][d] + part[1][qq][d] + part[2][qq][d] + part[3][qq][d];
    size_t ob = ((size_t)(b * TT + q0 + qq)) * HH + hoff + d;
    out[ob] = QN[ob] + o;
  }
}

// 256 blocks x 128 thr, 8 rows: LN + relu(x@W1^T+b1)@W2^T + b2 + x, keep-mask. W in LDS.
__global__ __launch_bounds__(128) void ffn_tiled(
    const float* __restrict__ S, const float* __restrict__ W1, const float* __restrict__ b1,
    const float* __restrict__ W2, const float* __restrict__ b2,
    const float* __restrict__ lng, const float* __restrict__ lnb,
    const int* __restrict__ log_seqs, float* __restrict__ outS) {
  int m0 = blockIdx.x * 8;
  int tid = threadIdx.x;
  int c = tid & 31, rg = tid >> 5;
  __shared__ float Ws[128][129];
  __shared__ float At[8][129];
  __shared__ float Hs[8][129];
  __shared__ float red[16];
  #pragma unroll
  for (int r = 0; r < 8; ++r) At[r][tid] = S[(size_t)(m0 + r) * HH + tid];
  for (int i = tid; i < 4096; i += 128) {
    int n = i >> 5, d = (i & 31) << 2;
    float4 wv = *(const float4*)(W1 + (size_t)n * HH + d);
    Ws[n][d] = wv.x; Ws[n][d+1] = wv.y; Ws[n][d+2] = wv.z; Ws[n][d+3] = wv.w;
  }
  __syncthreads();
  if (tid < 64) {
    int r = tid >> 3, sg = tid & 7;
    float s = 0.f;
    #pragma unroll
    for (int i = 0; i < 16; ++i) s += At[r][sg * 16 + i];
    s += __shfl_xor(s, 1); s += __shfl_xor(s, 2); s += __shfl_xor(s, 4);
    if (sg == 0) red[r] = s * (1.0f / HH);
  }
  __syncthreads();
  if (tid < 64) {
    int r = tid >> 3, sg = tid & 7;
    float mm = red[r], s = 0.f;
    #pragma unroll
    for (int i = 0; i < 16; ++i) { float dd = At[r][sg*16+i] - mm; s += dd * dd; }
    s += __shfl_xor(s, 1); s += __shfl_xor(s, 2); s += __shfl_xor(s, 4);
    if (sg == 0) red[8 + r] = rsqrtf(s * (1.0f / HH) + 1e-8f);
  }
  __syncthreads();
  {
    float gg = lng[tid], bb = lnb[tid];
    #pragma unroll
    for (int r = 0; r < 8; ++r)
      At[r][tid] = (At[r][tid] - red[r]) * red[8 + r] * gg + bb;
  }
  __syncthreads();
  float acc[2][4] = {{0.f,0.f,0.f,0.f},{0.f,0.f,0.f,0.f}};
  #pragma unroll 8
  for (int d = 0; d < 128; ++d) {
    float a0 = At[rg * 2 + 0][d];
    float a1 = At[rg * 2 + 1][d];
    float w0 = Ws[c][d], w1 = Ws[c + 32][d], w2 = Ws[c + 64][d], w3 = Ws[c + 96][d];
    acc[0][0] = fmaf(a0, w0, acc[0][0]); acc[0][1] = fmaf(a0, w1, acc[0][1]);
    acc[0][2] = fmaf(a0, w2, acc[0][2]); acc[0][3] = fmaf(a0, w3, acc[0][3]);
    acc[1][0] = fmaf(a1, w0, acc[1][0]); acc[1][1] = fmaf(a1, w1, acc[1][1]);
    acc[1][2] = fmaf(a1, w2, acc[1][2]); acc[1][3] = fmaf(a1, w3, acc[1][3]);
  }
  #pragma unroll
  for (int ri = 0; ri < 2; ++ri)
    #pragma unroll
    for (int j = 0; j < 4; ++j) {
      int n = c + 32 * j;
      Hs[rg * 2 + ri][n] = fmaxf(acc[ri][j] + b1[n], 0.f);
    }
  __syncthreads();
  for (int i = tid; i < 4096; i += 128) {
    int n = i >> 5, d = (i & 31) << 2;
    float4 wv = *(const float4*)(W2 + (size_t)n * HH + d);
    Ws[n][d] = wv.x; Ws[n][d+1] = wv.y; Ws[n][d+2] = wv.z; Ws[n][d+3] = wv.w;
  }
  __syncthreads();
  float acc2[2][4] = {{0.f,0.f,0.f,0.f},{0.f,0.f,0.f,0.f}};
  #pragma unroll 8
  for (int d = 0; d < 128; ++d) {
    float a0 = Hs[rg * 2 + 0][d];
    float a1 = Hs[rg * 2 + 1][d];
    float w0 = Ws[c][d], w1 = Ws[c + 32][d], w2 = Ws[c + 64][d], w3 = Ws[c + 96][d];
    acc2[0][0] = fmaf(a0, w0, acc2[0][0]); acc2[0][1] = fmaf(a0, w1, acc2[0][1]);
    acc2[0][2] = fmaf(a0, w2, acc2[0][2]); acc2[0][3] = fmaf(a0, w3, acc2[0][3]);
    acc2[1][0] = fmaf(a1, w0, acc2[1][0]); acc2[1][1] = fmaf(a1, w1, acc2[1][1]);
    acc2[1][2] = fmaf(a1, w2, acc2[1][2]); acc2[1][3] = fmaf(a1, w3, acc2[1][3]);
  }
  #pragma unroll
  for (int ri = 0; ri < 2; ++ri) {
    int m = m0 + rg * 2 + ri;
    int keep = (log_seqs[m] != 0);
    #pragma unroll
    for (int j = 0; j < 4; ++j) {
      int n = c + 32 * j;
      float v = acc2[ri][j] + b2[n] + At[rg * 2 + ri][n];
      outS[(size_t)m * HH + n] = keep ? v : 0.f;
    }
  }
}

// 256 blocks x 128 thr, 8 rows: last LN + gelu(x@fusW1[:, :128]^T + hp1)@fusW2^T + b2 + logits.
__global__ __launch_bounds__(128) void final_tiled(
    const float* __restrict__ S, const float* __restrict__ lng, const float* __restrict__ lnb,
    const float* __restrict__ fus_W1, const float* __restrict__ HP1,
    const float* __restrict__ fus_W2, const float* __restrict__ fus_b2,
    const float* __restrict__ item_emb, const int* __restrict__ pos,
    const int* __restrict__ neg, float* __restrict__ out) {
  int m0 = blockIdx.x * 8;
  int bidx = m0 >> 8;
  int tid = threadIdx.x;
  int c = tid & 31, rg = tid >> 5;
  __shared__ float Ws[128][129];
  __shared__ float At[8][129];
  __shared__ float Hs[8][129];
  __shared__ float red[16];
  #pragma unroll
  for (int r = 0; r < 8; ++r) At[r][tid] = S[(size_t)(m0 + r) * HH + tid];
  for (int i = tid; i < 4096; i += 128) {
    int n = i >> 5, d = (i & 31) << 2;
    float4 wv = *(const float4*)(fus_W1 + (size_t)n * 256 + d);
    Ws[n][d] = wv.x; Ws[n][d+1] = wv.y; Ws[n][d+2] = wv.z; Ws[n][d+3] = wv.w;
  }
  __syncthreads();
  if (tid < 64) {
    int r = tid >> 3, sg = tid & 7;
    float s = 0.f;
    #pragma unroll
    for (int i = 0; i < 16; ++i) s += At[r][sg * 16 + i];
    s += __shfl_xor(s, 1); s += __shfl_xor(s, 2); s += __shfl_xor(s, 4);
    if (sg == 0) red[r] = s * (1.0f / HH);
  }
  __syncthreads();
  if (tid < 64) {
    int r = tid >> 3, sg = tid & 7;
    float mm = red[r], s = 0.f;
    #pragma unroll
    for (int i = 0; i < 16; ++i) { float dd = At[r][sg*16+i] - mm; s += dd * dd; }
    s += __shfl_xor(s, 1); s += __shfl_xor(s, 2); s += __shfl_xor(s, 4);
    if (sg == 0) red[8 + r] = rsqrtf(s * (1.0f / HH) + 1e-8f);
  }
  __syncthreads();
  {
    float gg = lng[tid], bb = lnb[tid];
    #pragma unroll
    for (int r = 0; r < 8; ++r)
      At[r][tid] = (At[r][tid] - red[r]) * red[8 + r] * gg + bb;
  }
  __syncthreads();
  float acc[2][4] = {{0.f,0.f,0.f,0.f},{0.f,0.f,0.f,0.f}};
  #pragma unroll 8
  for (int d = 0; d < 128; ++d) {
    float a0 = At[rg * 2 + 0][d];
    float a1 = At[rg * 2 + 1][d];
    float w0 = Ws[c][d], w1 = Ws[c + 32][d], w2 = Ws[c + 64][d], w3 = Ws[c + 96][d];
    acc[0][0] = fmaf(a0, w0, acc[0][0]); acc[0][1] = fmaf(a0, w1, acc[0][1]);
    acc[0][2] = fmaf(a0, w2, acc[0][2]); acc[0][3] = fmaf(a0, w3, acc[0][3]);
    acc[1][0] = fmaf(a1, w0, acc[1][0]); acc[1][1] = fmaf(a1, w1, acc[1][1]);
    acc[1][2] = fmaf(a1, w2, acc[1][2]); acc[1][3] = fmaf(a1, w3, acc[1][3]);
  }
  #pragma unroll
  for (int ri = 0; ri < 2; ++ri)
    #pragma unroll
    for (int j = 0; j < 4; ++j) {
      int n = c + 32 * j;
      float v = acc[ri][j] + HP1[bidx * HH + n];
      Hs[rg * 2 + ri][n] = 0.5f * v * (1.0f + erff(v * 0.70710678118654752f));
    }
  __syncthreads();
  for (int i = tid; i < 4096; i += 128) {
    int n = i >> 5, d = (i & 31) << 2;
    float4 wv = *(const float4*)(fus_W2 + (size_t)n * HH + d);
    Ws[n][d] = wv.x; Ws[n][d+1] = wv.y; Ws[n][d+2] = wv.z; Ws[n][d+3] = wv.w;
  }
  __syncthreads();
  float acc2[2][4] = {{0.f,0.f,0.f,0.f},{0.f,0.f,0.f,0.f}};
  #pragma unroll 8
  for (int d = 0; d < 128; ++d) {
    float a0 = Hs[rg * 2 + 0][d];
    float a1 = Hs[rg * 2 + 1][d];
    float w0 = Ws[c][d], w1 = Ws[c + 32][d], w2 = Ws[c + 64][d], w3 = Ws[c + 96][d];
    acc2[0][0] = fmaf(a0, w0, acc2[0][0]); acc2[0][1] = fmaf(a0, w1, acc2[0][1]);
    acc2[0][2] = fmaf(a0, w2, acc2[0][2]); acc2[0][3] = fmaf(a0, w3, acc2[0][3]);
    acc2[1][0] = fmaf(a1, w0, acc2[1][0]); acc2[1][1] = fmaf(a1, w1, acc2[1][1]);
    acc2[1][2] = fmaf(a1, w2, acc2[1][2]); acc2[1][3] = fmaf(a1, w3, acc2[1][3]);
  }
  __syncthreads();
  #pragma unroll
  for (int ri = 0; ri < 2; ++ri)
    #pragma unroll
    for (int j = 0; j < 4; ++j) {
      int n = c + 32 * j;
      At[rg * 2 + ri][n] = acc2[ri][j] + fus_b2[n];
    }
  __syncthreads();
  {
    int task = tid >> 3;       // 0..15: r = task&7, pn = task>>3
    int sg = tid & 7;
    int r = task & 7;
    int pn = task >> 3;
    int mrow = m0 + r;
    int idx = pn ? neg[mrow] : pos[mrow];
    const float* ie = item_emb + (size_t)idx * HH;
    float s = 0.f;
    #pragma unroll
    for (int i = 0; i < 16; ++i) s += At[r][sg * 16 + i] * ie[sg * 16 + i];
    s += __shfl_xor(s, 1); s += __shfl_xor(s, 2); s += __shfl_xor(s, 4);
    if (sg == 0) out[pn * 2048 + mrow] = s;
  }
}

extern "C" void kernel_launch(void* const* d_in, const int* in_sizes, int n_in,
                              void* d_out, int out_size, void* d_ws, size_t ws_size,
                              hipStream_t stream) {
  const int*   log_seqs   = (const int*)d_in[0];
  const int*   tmat       = (const int*)d_in[1];
  const float* time_seq   = (const float*)d_in[2];
  const int*   pos_seqs   = (const int*)d_in[3];
  const int*   neg_seqs   = (const int*)d_in[4];
  const float* target_t   = (const float*)d_in[5];
  const float* item_emb   = (const float*)d_in[6];
  const float* abs_pos_K  = (const float*)d_in[7];
  const float* abs_pos_V  = (const float*)d_in[8];
  const float* time_K_emb = (const float*)d_in[9];
  const float* time_V_emb = (const float*)d_in[10];
  const float* Wq = (const float*)d_in[11];
  const float* bq = (const float*)d_in[12];
  const float* Wk = (const float*)d_in[13];
  const float* bk = (const float*)d_in[14];
  const float* Wv = (const float*)d_in[15];
  const float* bv = (const float*)d_in[16];
  const float* attn_ln_g = (const float*)d_in[17];
  const float* attn_ln_b = (const float*)d_in[18];
  const float* fwd_ln_g = (const float*)d_in[19];
  const float* fwd_ln_b = (const float*)d_in[20];
  const float* w1 = (const float*)d_in[21];
  const float* b1 = (const float*)d_in[22];
  const float* w2 = (const float*)d_in[23];
  const float* b2 = (const float*)d_in[24];
  const float* last_ln_g = (const float*)d_in[25];
  const float* last_ln_b = (const float*)d_in[26];
  const float* time_proj = (const float*)d_in[27];
  const float* lambdas = (const float*)d_in[28];
  const float* pred_W = (const float*)d_in[29];
  const float* fus_W1 = (const float*)d_in[30];
  const float* fus_b1 = (const float*)d_in[31];
  const float* fus_W2 = (const float*)d_in[32];
  const float* fus_b2 = (const float*)d_in[33];
  (void)in_sizes; (void)n_in; (void)out_size; (void)ws_size;

  float* out = (float*)d_out;
  float* ws = (float*)d_ws;
  const int M = 8 * TT;  // 2048
  float* SC6  = ws;                 // M*6
  float* SEQS = SC6 + M * 6;
  float* QN   = SEQS + M * HH;
  float* QB   = QN + M * HH;
  float* KT   = QB + M * HH;        // [b][h][d][t]
  float* VB   = KT + M * HH;
  float* HP1  = VB + M * HH;        // 8*128
  float* SCB  = HP1 + 8 * HH;       // 16*256*256 f32 = 4 MB

  embed_hper_kernel<<<2056, 128, 0, stream>>>(log_seqs, time_seq, item_emb, time_proj,
                                              target_t, pred_W, fus_W1, fus_b1,
                                              SEQS, SC6, HP1);
  for (int l = 0; l < 2; ++l) {
    const size_t wo = (size_t)l * HH * HH;
    const size_t bo = (size_t)l * HH;
    qkv_tiled<<<768, 128, 0, stream>>>(SEQS, Wq + wo, bq + bo, Wk + wo, bk + bo,
                                       Wv + wo, bv + bo, attn_ln_g + bo, attn_ln_b + bo,
                                       abs_pos_K, abs_pos_V, QN, QB, KT, VB);
    pkscb_kernel<<<1024, 256, 0, stream>>>(QB, time_K_emb, tmat, log_seqs, SC6, lambdas, SCB);
    attn_fused<<<2048, 256, 0, stream>>>(QB, KT, VB, QN, SCB, tmat, time_V_emb, SEQS);
    ffn_tiled<<<256, 128, 0, stream>>>(SEQS, w1 + wo, b1 + bo, w2 + wo, b2 + bo,
                                       fwd_ln_g + bo, fwd_ln_b + bo, log_seqs, SEQS);
  }
  final_tiled<<<256, 128, 0, stream>>>(SEQS, last_ln_g, last_ln_b, fus_W1, HP1,
                                       fus_W2, fus_b2, item_emb, pos_seqs, neg_seqs, out);
}

// Round 10
// 305.702 us; speedup vs baseline: 1.3770x; 1.0472x over previous
//
#include <hip/hip_runtime.h>
#include <math.h>

#define TT 256
#define HH 128

__device__ __forceinline__ void enc6(float t, float e[6]) {
  float x = 6.2831853071795864769f * t;
  float a0 = x / 86400.0f, a1 = x / 604800.0f, a2 = x / 2592000.0f;
  e[0] = sinf(a0); e[1] = sinf(a1); e[2] = sinf(a2);
  e[3] = cosf(a0); e[4] = cosf(a1); e[5] = cosf(a2);
}

__device__ __forceinline__ float wave_sum(float s) {
  #pragma unroll
  for (int o = 32; o > 0; o >>= 1) s += __shfl_xor(s, o);
  return s;
}

// blocks 0..2047: embed row (+ QN0 = LN(row, attn_ln[0])); 2048..2055: hper.
__global__ __launch_bounds__(128) void embed_hper_kernel(
    const int* __restrict__ log_seqs, const float* __restrict__ time_seq,
    const float* __restrict__ item_emb, const float* __restrict__ time_proj,
    const float* __restrict__ target_t, const float* __restrict__ pred_W,
    const float* __restrict__ fus_W1, const float* __restrict__ fus_b1,
    const float* __restrict__ ln0g, const float* __restrict__ ln0b,
    float* __restrict__ seqs, float* __restrict__ sc6,
    float* __restrict__ QN, float* __restrict__ hp1) {
  int blk = blockIdx.x;
  int tid = threadIdx.x;
  __shared__ float redE[4];
  __shared__ float te[HH], hp[HH];
  if (blk < 2048) {
    float t = time_seq[blk];
    float e[6]; enc6(t, e);
    int idx = log_seqs[blk];
    const float* tp = time_proj + tid * 6;
    float val = item_emb[(size_t)idx * HH + tid] * 11.313708498984761f; // sqrt(128)
    val += e[0]*tp[0] + e[1]*tp[1] + e[2]*tp[2] + e[3]*tp[3] + e[4]*tp[4] + e[5]*tp[5];
    if (idx == 0) val = 0.0f;
    seqs[(size_t)blk * HH + tid] = val;
    if (tid < 6) sc6[blk * 6 + tid] = e[tid];
    int w = tid >> 6;
    float s = wave_sum(val);
    if ((tid & 63) == 0) redE[w] = s;
    __syncthreads();
    float mu = (redE[0] + redE[1]) * (1.0f / HH);
    float dv = val - mu;
    float v2 = wave_sum(dv * dv);
    if ((tid & 63) == 0) redE[2 + w] = v2;
    __syncthreads();
    float var = (redE[2] + redE[3]) * (1.0f / HH);
    QN[(size_t)blk * HH + tid] = dv * rsqrtf(var + 1e-8f) * ln0g[tid] + ln0b[tid];
  } else {
    int b = blk - 2048;
    float e[6]; enc6(target_t[b], e);
    const float* tp = time_proj + tid * 6;
    te[tid] = e[0]*tp[0]+e[1]*tp[1]+e[2]*tp[2]+e[3]*tp[3]+e[4]*tp[4]+e[5]*tp[5];
    __syncthreads();
    float u = 0.f;
    const float* pw = pred_W + (size_t)tid * HH;
    for (int d = 0; d < HH; ++d) u += te[d] * pw[d];
    hp[tid] = u;
    __syncthreads();
    float w = fus_b1[tid];
    const float* f1 = fus_W1 + (size_t)tid * 256 + 128;
    for (int d = 0; d < HH; ++d) w += hp[d] * f1[d];
    hp1[b * HH + tid] = w;
  }
}

// Register-prefetch GEMM: 1536 blocks x 128 thr; which = blk>>9 (0=Q from QN, 1=K+absK->KT, 2=V+absV).
// 4 rows/block, thread owns col n=tid; W row prefetched into 32 float4 regs (MLP);
// A read via block-uniform (scalar) global loads.
__global__ __launch_bounds__(128) void qkv_reg(
    const float* __restrict__ S, const float* __restrict__ QN,
    const float* __restrict__ Wq, const float* __restrict__ bq,
    const float* __restrict__ Wk, const float* __restrict__ bk,
    const float* __restrict__ Wv, const float* __restrict__ bv,
    const float* __restrict__ absK, const float* __restrict__ absV,
    float* __restrict__ QB, float* __restrict__ KT, float* __restrict__ VB) {
  int blk = blockIdx.x;
  int which = blk >> 9;
  int m0 = (blk & 511) * 4;
  int tid = threadIdx.x;
  const float* W = which == 0 ? Wq : which == 1 ? Wk : Wv;
  const float* Ab = which == 0 ? QN : S;
  float4 wreg[32];
  {
    const float4* wr4 = (const float4*)(W + (size_t)tid * HH);
    #pragma unroll
    for (int i = 0; i < 32; ++i) wreg[i] = wr4[i];
  }
  float acc[4] = {0.f, 0.f, 0.f, 0.f};
  #pragma unroll
  for (int s = 0; s < 32; ++s) {
    int d = s << 2;
    float4 w4 = wreg[s];
    #pragma unroll
    for (int r = 0; r < 4; ++r) {
      const float* ar = Ab + (size_t)(m0 + r) * HH + d;
      acc[r] = fmaf(ar[0], w4.x, fmaf(ar[1], w4.y, fmaf(ar[2], w4.z, fmaf(ar[3], w4.w, acc[r]))));
    }
  }
  const float* bias = which == 0 ? bq : which == 1 ? bk : bv;
  float bn = bias[tid];
  #pragma unroll
  for (int r = 0; r < 4; ++r) {
    int m = m0 + r;
    int t = m & 255, bb2 = m >> 8;
    float v = acc[r] + bn;
    if (which == 0) {
      QB[(size_t)m * HH + tid] = v;
    } else if (which == 1) {
      v += absK[(size_t)t * HH + tid];
      KT[(((size_t)(bb2 * 2 + (tid >> 6)) * 64) + (tid & 63)) * 256 + t] = v;
    } else {
      v += absV[(size_t)t * HH + tid];
      VB[(size_t)m * HH + tid] = v;
    }
  }
}

// SCB[bh,q,k] = mask ? -1e9 : 0.125*(q . tKe[tm[b,q,k]]) + phase_bias(q,k)
__global__ __launch_bounds__(256) void pkscb_kernel(
    const float* __restrict__ QB, const float* __restrict__ tKe,
    const int* __restrict__ tmat, const int* __restrict__ log_seqs,
    const float* __restrict__ sc6, const float* __restrict__ lambdas,
    float* __restrict__ SCB) {
  int blk = blockIdx.x;
  int qt = blk & 63, bh = blk >> 6;
  int h = bh & 1, b = bh >> 1;
  int q0 = qt << 2, hoff = h << 6;
  int tid = threadIdx.x;
  __shared__ float Qs[4][64];
  __shared__ float PKl[4][264];
  __shared__ float sk6T[6][256];
  __shared__ float sq6[4][6];
  __shared__ unsigned char kmask[256];
  { int q = tid >> 6, d = tid & 63;
    Qs[q][d] = QB[((size_t)(b * TT + q0 + q)) * HH + hoff + d]; }
  for (int idx = tid; idx < 1536; idx += 256) {
    int kk = idx / 6, cc = idx - kk * 6;
    sk6T[cc][kk] = sc6[(size_t)b * 1536 + idx];
  }
  if (tid < 24) {
    int q = tid / 6, cc = tid - q * 6;
    sq6[q][cc] = sc6[((size_t)(b * TT + q0 + q)) * 6 + cc];
  }
  kmask[tid] = (log_seqs[b * TT + tid] == 0) ? 1 : 0;
  __syncthreads();
  for (int i = tid; i < 257; i += 256) {
    const float* tp = tKe + (size_t)i * HH + hoff;
    float a0 = 0.f, a1 = 0.f, a2 = 0.f, a3 = 0.f;
    #pragma unroll
    for (int d = 0; d < 64; d += 4) {
      float4 t4 = *(const float4*)(tp + d);
      float4 v0 = *(const float4*)(&Qs[0][d]);
      float4 v1 = *(const float4*)(&Qs[1][d]);
      float4 v2 = *(const float4*)(&Qs[2][d]);
      float4 v3 = *(const float4*)(&Qs[3][d]);
      a0 = fmaf(v0.x,t4.x,fmaf(v0.y,t4.y,fmaf(v0.z,t4.z,fmaf(v0.w,t4.w,a0))));
      a1 = fmaf(v1.x,t4.x,fmaf(v1.y,t4.y,fmaf(v1.z,t4.z,fmaf(v1.w,t4.w,a1))));
      a2 = fmaf(v2.x,t4.x,fmaf(v2.y,t4.y,fmaf(v2.z,t4.z,fmaf(v2.w,t4.w,a2))));
      a3 = fmaf(v3.x,t4.x,fmaf(v3.y,t4.y,fmaf(v3.z,t4.z,fmaf(v3.w,t4.w,a3))));
    }
    PKl[0][i] = a0 * 0.125f; PKl[1][i] = a1 * 0.125f;
    PKl[2][i] = a2 * 0.125f; PKl[3][i] = a3 * 0.125f;
  }
  __syncthreads();
  float l0 = lambdas[0], l1 = lambdas[1], l2 = lambdas[2];
  int k = tid;
  float c0 = sk6T[0][k], c1 = sk6T[1][k], c2 = sk6T[2][k],
        c3 = sk6T[3][k], c4 = sk6T[4][k], c5 = sk6T[5][k];
  int km = kmask[k];
  float* scbq = SCB + ((size_t)(bh * TT + q0)) * TT;
  #pragma unroll
  for (int qq = 0; qq < 4; ++qq) {
    int qg = q0 + qq;
    float pb = l0 * (sq6[qq][0] * c0 + sq6[qq][3] * c3)
             + l1 * (sq6[qq][1] * c1 + sq6[qq][4] * c4)
             + l2 * (sq6[qq][2] * c2 + sq6[qq][5] * c5);
    int tm = tmat[((size_t)(b * TT + qg)) * TT + k];
    float val = (k > qg || km) ? -1e9f : (PKl[qq][tm] + pb);
    scbq[(size_t)qq * TT + k] = val;
  }
}

// grid: 2048 blocks (XCD-swizzled), 256 thr, 2 q-rows per block.
__global__ __launch_bounds__(256) void attn_fused(
    const float* __restrict__ QB, const float* __restrict__ KT,
    const float* __restrict__ VB, const float* __restrict__ QN,
    const float* __restrict__ SCB, const int* __restrict__ tmat,
    const float* __restrict__ tVe, float* __restrict__ out) {
  int blk = blockIdx.x;
  blk = (blk & 7) * 256 + (blk >> 3);   // bijective XCD swizzle (2048 = 8*256)
  int qt = blk & 127;
  int h = (blk >> 7) & 1;
  int b = blk >> 8;
  int q0 = qt << 1;
  int hoff = h << 6;
  int tid = threadIdx.x;
  int w = tid >> 6, lane = tid & 63;

  __shared__ float Qt[2][64];
  __shared__ float Pp[2][256];
  __shared__ unsigned short tmq[2][256];
  __shared__ float part[4][2][64];
  __shared__ float red[16];

  if (tid < 128)
    Qt[tid >> 6][tid & 63] = QB[((size_t)(b * TT + q0 + (tid >> 6))) * HH + hoff + (tid & 63)];
  #pragma unroll
  for (int t = 0; t < 2; ++t) {
    int idx = tid + t * 256;
    int qq = idx >> 8, kk = idx & 255;
    tmq[qq][kk] = (unsigned short)tmat[((size_t)(b * TT + q0 + qq)) * TT + kk];
  }
  __syncthreads();

  int k = (w << 6) | lane;
  const float* scb0 = SCB + ((size_t)((b * 2 + h) * TT + q0)) * TT;
  float s0 = scb0[k];
  float s1 = scb0[TT + k];
  if ((w << 6) <= q0 + 1) {
    float a0 = 0.f, a1 = 0.f;
    const float* ktb = KT + ((size_t)((b * 2 + h) * 64)) * 256 + k;
    #pragma unroll
    for (int d4 = 0; d4 < 16; ++d4) {
      float4 qa = *(const float4*)(&Qt[0][d4 << 2]);
      float4 qb = *(const float4*)(&Qt[1][d4 << 2]);
      const float* kp = ktb + (size_t)(d4 << 2) * 256;
      float v0 = kp[0], v1 = kp[256], v2 = kp[512], v3 = kp[768];
      a0 = fmaf(qa.x, v0, fmaf(qa.y, v1, fmaf(qa.z, v2, fmaf(qa.w, v3, a0))));
      a1 = fmaf(qb.x, v0, fmaf(qb.y, v1, fmaf(qb.z, v2, fmaf(qb.w, v3, a1))));
    }
    if (s0 > -5e8f) s0 = fmaf(a0, 0.125f, s0);
    if (s1 > -5e8f) s1 = fmaf(a1, 0.125f, s1);
  }
  float m0 = s0, m1 = s1;
  #pragma unroll
  for (int o = 32; o > 0; o >>= 1) {
    m0 = fmaxf(m0, __shfl_xor(m0, o));
    m1 = fmaxf(m1, __shfl_xor(m1, o));
  }
  if (lane == 0) { red[w] = m0; red[4 + w] = m1; }
  __syncthreads();
  float gm0 = fmaxf(fmaxf(red[0], red[1]), fmaxf(red[2], red[3]));
  float gm1 = fmaxf(fmaxf(red[4], red[5]), fmaxf(red[6], red[7]));
  float p0 = (gm0 < -5e8f) ? 1.0f : __expf(s0 - gm0);
  float p1 = (gm1 < -5e8f) ? 1.0f : __expf(s1 - gm1);
  float u0 = p0, u1 = p1;
  #pragma unroll
  for (int o = 32; o > 0; o >>= 1) {
    u0 += __shfl_xor(u0, o);
    u1 += __shfl_xor(u1, o);
  }
  if (lane == 0) { red[8 + w] = u0; red[12 + w] = u1; }
  __syncthreads();
  float inv0 = 1.0f / (red[8] + red[9] + red[10] + red[11]);
  float inv1 = 1.0f / (red[12] + red[13] + red[14] + red[15]);
  Pp[0][k] = p0 * inv0;
  Pp[1][k] = p1 * inv1;
  __syncthreads();

  int kend = (gm0 < -5e8f || gm1 < -5e8f) ? 256 : (q0 + 2);
  float o0 = 0.f, o1 = 0.f;
  const float* vbase = VB + ((size_t)(b * TT)) * HH + hoff + lane;
  const float* tvb   = tVe + hoff + lane;
  for (int kk = w; kk < kend; kk += 4) {
    float pa  = Pp[0][kk];
    float pb2 = Pp[1][kk];
    int ta = tmq[0][kk], tb = tmq[1][kk];
    float v  = vbase[(size_t)kk * HH];
    float t0 = tvb[(size_t)ta * HH];
    float t1 = tvb[(size_t)tb * HH];
    o0 = fmaf(pa,  v + t0, o0);
    o1 = fmaf(pb2, v + t1, o1);
  }
  part[w][0][lane] = o0;
  part[w][1][lane] = o1;
  __syncthreads();
  if (tid < 128) {
    int qq = tid >> 6, d = tid & 63;
    float o = part[0][qq][d] + part[1][qq][d] + part[2][qq][d] + part[3][qq][d];
    size_t ob = ((size_t)(b * TT + q0 + qq)) * HH + hoff + d;
    out[ob] = QN[ob] + o;
  }
}

// 512 blocks x 128 thr, 4 rows: LN + FFN + residual + keep-mask; also writes
// next-stage LN'd copy (QN for next layer, or FN for the head).
__global__ __launch_bounds__(128) void ffn_reg(
    const float* __restrict__ S, const float* __restrict__ W1, const float* __restrict__ b1,
    const float* __restrict__ W2, const float* __restrict__ b2,
    const float* __restrict__ lng, const float* __restrict__ lnb,
    const int* __restrict__ log_seqs,
    const float* __restrict__ nlng, const float* __restrict__ nlnb,
    float* __restrict__ outS, float* __restrict__ outXN) {
  int m0 = blockIdx.x * 4;
  int tid = threadIdx.x;
  __shared__ float Xt[4][HH];
  __shared__ float Hs[4][HH];
  __shared__ float red[16];
  #pragma unroll
  for (int r = 0; r < 4; ++r) Xt[r][tid] = S[(size_t)(m0 + r) * HH + tid];
  __syncthreads();
  if (tid < 32) {
    int r = tid >> 3, sg = tid & 7;
    float s = 0.f;
    #pragma unroll
    for (int i = 0; i < 16; ++i) s += Xt[r][sg * 16 + i];
    s += __shfl_xor(s, 1); s += __shfl_xor(s, 2); s += __shfl_xor(s, 4);
    if (sg == 0) red[r] = s * (1.0f / HH);
  }
  __syncthreads();
  if (tid < 32) {
    int r = tid >> 3, sg = tid & 7;
    float mm = red[r], s = 0.f;
    #pragma unroll
    for (int i = 0; i < 16; ++i) { float dd = Xt[r][sg*16+i] - mm; s += dd * dd; }
    s += __shfl_xor(s, 1); s += __shfl_xor(s, 2); s += __shfl_xor(s, 4);
    if (sg == 0) red[8 + r] = rsqrtf(s * (1.0f / HH) + 1e-8f);
  }
  __syncthreads();
  {
    float gg = lng[tid], bb = lnb[tid];
    #pragma unroll
    for (int r = 0; r < 4; ++r)
      Xt[r][tid] = (Xt[r][tid] - red[r]) * red[8 + r] * gg + bb;
  }
  __syncthreads();
  float4 wreg[32];
  {
    const float4* w4p = (const float4*)(W1 + (size_t)tid * HH);
    #pragma unroll
    for (int i = 0; i < 32; ++i) wreg[i] = w4p[i];
  }
  float acc[4] = {0.f, 0.f, 0.f, 0.f};
  #pragma unroll
  for (int s = 0; s < 32; ++s) {
    int d = s << 2;
    float4 w4 = wreg[s];
    #pragma unroll
    for (int r = 0; r < 4; ++r) {
      float4 a = *(const float4*)(&Xt[r][d]);
      acc[r] = fmaf(a.x, w4.x, fmaf(a.y, w4.y, fmaf(a.z, w4.z, fmaf(a.w, w4.w, acc[r]))));
    }
  }
  {
    float b1n = b1[tid];
    #pragma unroll
    for (int r = 0; r < 4; ++r) Hs[r][tid] = fmaxf(acc[r] + b1n, 0.f);
  }
  __syncthreads();
  {
    const float4* w4p = (const float4*)(W2 + (size_t)tid * HH);
    #pragma unroll
    for (int i = 0; i < 32; ++i) wreg[i] = w4p[i];
  }
  float acc2[4] = {0.f, 0.f, 0.f, 0.f};
  #pragma unroll
  for (int s = 0; s < 32; ++s) {
    int d = s << 2;
    float4 w4 = wreg[s];
    #pragma unroll
    for (int r = 0; r < 4; ++r) {
      float4 a = *(const float4*)(&Hs[r][d]);
      acc2[r] = fmaf(a.x, w4.x, fmaf(a.y, w4.y, fmaf(a.z, w4.z, fmaf(a.w, w4.w, acc2[r]))));
    }
  }
  {
    float b2n = b2[tid];
    #pragma unroll
    for (int r = 0; r < 4; ++r) {
      int m = m0 + r;
      float v = acc2[r] + b2n + Xt[r][tid];
      if (log_seqs[m] == 0) v = 0.f;
      outS[(size_t)m * HH + tid] = v;
      Xt[r][tid] = v;   // reuse for next-LN
    }
  }
  __syncthreads();
  if (tid < 32) {
    int r = tid >> 3, sg = tid & 7;
    float s = 0.f;
    #pragma unroll
    for (int i = 0; i < 16; ++i) s += Xt[r][sg * 16 + i];
    s += __shfl_xor(s, 1); s += __shfl_xor(s, 2); s += __shfl_xor(s, 4);
    if (sg == 0) red[r] = s * (1.0f / HH);
  }
  __syncthreads();
  if (tid < 32) {
    int r = tid >> 3, sg = tid & 7;
    float mm = red[r], s = 0.f;
    #pragma unroll
    for (int i = 0; i < 16; ++i) { float dd = Xt[r][sg*16+i] - mm; s += dd * dd; }
    s += __shfl_xor(s, 1); s += __shfl_xor(s, 2); s += __shfl_xor(s, 4);
    if (sg == 0) red[8 + r] = rsqrtf(s * (1.0f / HH) + 1e-8f);
  }
  __syncthreads();
  {
    float gg = nlng[tid], bb = nlnb[tid];
    #pragma unroll
    for (int r = 0; r < 4; ++r)
      outXN[(size_t)(m0 + r) * HH + tid] = (Xt[r][tid] - red[r]) * red[8 + r] * gg + bb;
  }
}

// 512 blocks x 128 thr, 4 rows: gelu(FN@fusW1[:, :128]^T + hp1)@fusW2^T + b2 -> logits.
// FN is pre-LN'd (from ffn_reg) so GEMM1 A is scalar-uniform.
__global__ __launch_bounds__(128) void final_reg(
    const float* __restrict__ FN, const float* __restrict__ fus_W1,
    const float* __restrict__ HP1, const float* __restrict__ fus_W2,
    const float* __restrict__ fus_b2, const float* __restrict__ item_emb,
    const int* __restrict__ pos, const int* __restrict__ neg,
    float* __restrict__ out) {
  int m0 = blockIdx.x * 4;
  int bidx = m0 >> 8;
  int tid = threadIdx.x;
  __shared__ float Hs[4][HH];
  __shared__ float Ft[4][HH];
  float4 wreg[32];
  {
    const float4* w4p = (const float4*)(fus_W1 + (size_t)tid * 256);
    #pragma unroll
    for (int i = 0; i < 32; ++i) wreg[i] = w4p[i];
  }
  float acc[4] = {0.f, 0.f, 0.f, 0.f};
  #pragma unroll
  for (int s = 0; s < 32; ++s) {
    int d = s << 2;
    float4 w4 = wreg[s];
    #pragma unroll
    for (int r = 0; r < 4; ++r) {
      const float* ar = FN + (size_t)(m0 + r) * HH + d;
      acc[r] = fmaf(ar[0], w4.x, fmaf(ar[1], w4.y, fmaf(ar[2], w4.z, fmaf(ar[3], w4.w, acc[r]))));
    }
  }
  {
    float hpv = HP1[bidx * HH + tid];
    #pragma unroll
    for (int r = 0; r < 4; ++r) {
      float v = acc[r] + hpv;
      Hs[r][tid] = 0.5f * v * (1.0f + erff(v * 0.70710678118654752f));
    }
  }
  __syncthreads();
  {
    const float4* w4p = (const float4*)(fus_W2 + (size_t)tid * HH);
    #pragma unroll
    for (int i = 0; i < 32; ++i) wreg[i] = w4p[i];
  }
  float acc2[4] = {0.f, 0.f, 0.f, 0.f};
  #pragma unroll
  for (int s = 0; s < 32; ++s) {
    int d = s << 2;
    float4 w4 = wreg[s];
    #pragma unroll
    for (int r = 0; r < 4; ++r) {
      float4 a = *(const float4*)(&Hs[r][d]);
      acc2[r] = fmaf(a.x, w4.x, fmaf(a.y, w4.y, fmaf(a.z, w4.z, fmaf(a.w, w4.w, acc2[r]))));
    }
  }
  {
    float b2n = fus_b2[tid];
    #pragma unroll
    for (int r = 0; r < 4; ++r) Ft[r][tid] = acc2[r] + b2n;
  }
  __syncthreads();
  {
    int task = tid >> 4;       // 0..7: r = task&3, pn = task>>2
    int sg = tid & 15;
    int r = task & 3;
    int pn = task >> 2;
    int mrow = m0 + r;
    int idx = pn ? neg[mrow] : pos[mrow];
    const float* ie = item_emb + (size_t)idx * HH;
    float s = 0.f;
    #pragma unroll
    for (int i = 0; i < 8; ++i) s += Ft[r][sg * 8 + i] * ie[sg * 8 + i];
    s += __shfl_xor(s, 1); s += __shfl_xor(s, 2);
    s += __shfl_xor(s, 4); s += __shfl_xor(s, 8);
    if (sg == 0) out[pn * 2048 + mrow] = s;
  }
}

extern "C" void kernel_launch(void* const* d_in, const int* in_sizes, int n_in,
                              void* d_out, int out_size, void* d_ws, size_t ws_size,
                              hipStream_t stream) {
  const int*   log_seqs   = (const int*)d_in[0];
  const int*   tmat       = (const int*)d_in[1];
  const float* time_seq   = (const float*)d_in[2];
  const int*   pos_seqs   = (const int*)d_in[3];
  const int*   neg_seqs   = (const int*)d_in[4];
  const float* target_t   = (const float*)d_in[5];
  const float* item_emb   = (const float*)d_in[6];
  const float* abs_pos_K  = (const float*)d_in[7];
  const float* abs_pos_V  = (const float*)d_in[8];
  const float* time_K_emb = (const float*)d_in[9];
  const float* time_V_emb = (const float*)d_in[10];
  const float* Wq = (const float*)d_in[11];
  const float* bq = (const float*)d_in[12];
  const float* Wk = (const float*)d_in[13];
  const float* bk = (const float*)d_in[14];
  const float* Wv = (const float*)d_in[15];
  const float* bv = (const float*)d_in[16];
  const float* attn_ln_g = (const float*)d_in[17];
  const float* attn_ln_b = (const float*)d_in[18];
  const float* fwd_ln_g = (const float*)d_in[19];
  const float* fwd_ln_b = (const float*)d_in[20];
  const float* w1 = (const float*)d_in[21];
  const float* b1 = (const float*)d_in[22];
  const float* w2 = (const float*)d_in[23];
  const float* b2 = (const float*)d_in[24];
  const float* last_ln_g = (const float*)d_in[25];
  const float* last_ln_b = (const float*)d_in[26];
  const float* time_proj = (const float*)d_in[27];
  const float* lambdas = (const float*)d_in[28];
  const float* pred_W = (const float*)d_in[29];
  const float* fus_W1 = (const float*)d_in[30];
  const float* fus_b1 = (const float*)d_in[31];
  const float* fus_W2 = (const float*)d_in[32];
  const float* fus_b2 = (const float*)d_in[33];
  (void)in_sizes; (void)n_in; (void)out_size; (void)ws_size;

  float* out = (float*)d_out;
  float* ws = (float*)d_ws;
  const int M = 8 * TT;  // 2048
  float* SC6  = ws;                 // M*6
  float* SEQS = SC6 + M * 6;
  float* QN   = SEQS + M * HH;
  float* QB   = QN + M * HH;
  float* KT   = QB + M * HH;        // [b][h][d][t]
  float* VB   = KT + M * HH;
  float* FN   = VB + M * HH;        // pre-LN'd input for the head
  float* HP1  = FN + M * HH;        // 8*128
  float* SCB  = HP1 + 8 * HH;       // 16*256*256 f32 = 4 MB

  embed_hper_kernel<<<2056, 128, 0, stream>>>(log_seqs, time_seq, item_emb, time_proj,
                                              target_t, pred_W, fus_W1, fus_b1,
                                              attn_ln_g, attn_ln_b,
                                              SEQS, SC6, QN, HP1);
  for (int l = 0; l < 2; ++l) {
    const size_t wo = (size_t)l * HH * HH;
    const size_t bo = (size_t)l * HH;
    qkv_reg<<<1536, 128, 0, stream>>>(SEQS, QN, Wq + wo, bq + bo, Wk + wo, bk + bo,
                                      Wv + wo, bv + bo, abs_pos_K, abs_pos_V,
                                      QB, KT, VB);
    pkscb_kernel<<<1024, 256, 0, stream>>>(QB, time_K_emb, tmat, log_seqs, SC6, lambdas, SCB);
    attn_fused<<<2048, 256, 0, stream>>>(QB, KT, VB, QN, SCB, tmat, time_V_emb, SEQS);
    const float* nlng = (l == 0) ? (attn_ln_g + HH) : last_ln_g;
    const float* nlnb = (l == 0) ? (attn_ln_b + HH) : last_ln_b;
    float* outXN = (l == 0) ? QN : FN;
    ffn_reg<<<512, 128, 0, stream>>>(SEQS, w1 + wo, b1 + bo, w2 + wo, b2 + bo,
                                     fwd_ln_g + bo, fwd_ln_b + bo, log_seqs,
                                     nlng, nlnb, SEQS, outXN);
  }
  final_reg<<<512, 128, 0, stream>>>(FN, fus_W1, HP1, fus_W2, fus_b2,
                                     item_emb, pos_seqs, neg_seqs, out);
}